// Round 6
// baseline (216.026 us; speedup 1.0000x reference)
//
#include <hip/hip_runtime.h>
#include <math.h>

#define NPTS 8192
#define NB 2
#define NROWS (NB * NPTS)
#define KNN 16
#define CAP 64        // collect capacity per row per list
#define STEPS (NPTS / 64)                  // 128

// pass1 geometry: 1024-thread blocks, 16 waves x 4 rows = 64 rows/block
#define P1_G 4
#define P1_ROWS 64
#define P1_BLOCKS (NROWS / P1_ROWS)        // 256
#define P1_PER_BATCH (P1_BLOCKS / NB)      // 128

// knn geometry: 128-thread blocks (2 waves) x 4 rows = 8 rows/block ->
// 2048 blocks (16/CU: occupancy AND 4-row load amortization), plus 128
// trailing blocks that combine the colmin partials.
#define K_G 4
#define K_ROWS 8
#define K_BLOCKS (NROWS / K_ROWS)          // 2048
#define CMB_BLOCKS (NROWS / 128)           // 128

#define INF_BITS 0x7F800000u

__device__ __forceinline__ float sqd3(float qx, float qy, float qz, float4 c) {
  float dx = qx - c.x, dy = qy - c.y, dz = qz - c.z;
  return fmaf(dx, dx, fmaf(dy, dy, dz * dz));
}

__device__ __forceinline__ int lanerank(unsigned long long mk) {
  // # of set bits in mk strictly below this lane
  return __builtin_amdgcn_mbcnt_hi((unsigned)(mk >> 32),
                                   __builtin_amdgcn_mbcnt_lo((unsigned)mk, 0));
}

// Full ascending bitonic sort of one value per lane across the 64-lane wave.
__device__ __forceinline__ float bitonic_sort64(float v, int lane) {
#pragma unroll
  for (int k = 2; k <= 64; k <<= 1) {
#pragma unroll
    for (int j = k >> 1; j >= 1; j >>= 1) {
      float o = __shfl_xor(v, j, 64);
      bool up = ((lane & k) == 0);
      bool lower = ((lane & j) == 0);
      float mn = fminf(v, o), mx = fmaxf(v, o);
      v = (up == lower) ? mn : mx;
    }
  }
  return v;
}

// Pad [N,3] points to float4 for aligned dwordx4 loads.
__global__ __launch_bounds__(256) void repack_kernel(
    const float* __restrict__ yp, const float* __restrict__ yt,
    float4* __restrict__ P4, float4* __restrict__ T4) {
  int i = blockIdx.x * 256 + threadIdx.x;
  if (i < NROWS) {
    P4[i] = make_float4(yp[3 * i], yp[3 * i + 1], yp[3 * i + 2], 0.0f);
    T4[i] = make_float4(yt[3 * i], yt[3 * i + 1], yt[3 * i + 2], 0.0f);
  }
}

// Pass 1: per true-point row, per-lane min over 128 candidates for both lists
// (sorted lane-minima -> exact minrow + provable 16-NN bound tau: the 16
// smallest lane-minima are 16 distinct candidates <= tau). Column minima
// (mincol) ride along via LDS atomicMin -> per-block partial in ws.
// Linear pointer walk (no modular wrap): prefetch may read up to 2 steps past
// the batch slice, which lands in the next ws array — always mapped.
__global__ __launch_bounds__(1024) void pass1_kernel(
    const float4* __restrict__ P4, const float4* __restrict__ T4,
    float* __restrict__ tauP, float* __restrict__ tauT,
    float* __restrict__ minrow_arr, unsigned* __restrict__ colmin_part) {
  __shared__ unsigned colmin[NPTS];   // 32 KB, uint bits of nonneg float
  const int wave = threadIdx.x >> 6, lane = threadIdx.x & 63;
  const int r0 = blockIdx.x * P1_ROWS + wave * P1_G;
  const int b = r0 >> 13;
  const int i0 = r0 & (NPTS - 1);
  const float4* Pb = P4 + ((size_t)b << 13);
  const float4* Tb = T4 + ((size_t)b << 13);

  for (int u = threadIdx.x; u < NPTS; u += 1024) colmin[u] = INF_BITS;

  float qx[P1_G], qy[P1_G], qz[P1_G], mP[P1_G], mT[P1_G];
#pragma unroll
  for (int r = 0; r < P1_G; ++r) {
    float4 q = Tb[i0 + r];
    qx[r] = q.x; qy[r] = q.y; qz[r] = q.z;
    mP[r] = INFINITY; mT[r] = INFINITY;
  }
  __syncthreads();

  const float4* pP = Pb + lane;
  const float4* pT = Tb + lane;
  unsigned cmi = lane;                // colmin word index for step s
  float4 cP0 = pP[0], cP1 = pP[64];
  float4 cT0 = pT[0], cT1 = pT[64];
  for (int s = 0; s < STEPS; s += 2) {
    float4 nP0 = pP[128], nP1 = pP[192];   // imm offsets 2048/3072 B
    float4 nT0 = pT[128], nT1 = pT[192];
    float d0[P1_G], d1[P1_G];
#pragma unroll
    for (int r = 0; r < P1_G; ++r) {
      d0[r] = sqd3(qx[r], qy[r], qz[r], cP0);
      mP[r] = fminf(mP[r], d0[r]);
      d1[r] = sqd3(qx[r], qy[r], qz[r], cP1);
      mP[r] = fminf(mP[r], d1[r]);
    }
    float cm0 = fminf(fminf(d0[0], d0[1]), fminf(d0[2], d0[3]));
    float cm1 = fminf(fminf(d1[0], d1[1]), fminf(d1[2], d1[3]));
    atomicMin(&colmin[cmi], __float_as_uint(cm0));        // 2 lanes/bank: free
    atomicMin(&colmin[cmi + 64], __float_as_uint(cm1));
#pragma unroll
    for (int r = 0; r < P1_G; ++r) {
      mT[r] = fminf(mT[r], sqd3(qx[r], qy[r], qz[r], cT0));
      mT[r] = fminf(mT[r], sqd3(qx[r], qy[r], qz[r], cT1));
    }
    pP += 128; pT += 128; cmi += 128;
    cP0 = nP0; cP1 = nP1; cT0 = nT0; cT1 = nT1;
  }
  __syncthreads();

  // block-partial column minima -> ws
  unsigned* part = colmin_part + (size_t)blockIdx.x * NPTS;
  for (int u = threadIdx.x; u < NPTS; u += 1024) part[u] = colmin[u];

  // per-row epilogue: sort 64 lane-minima
#pragma unroll 1
  for (int r = 0; r < P1_G; ++r) {
    float v = bitonic_sort64(mP[r], lane);
    if (lane == 0) minrow_arr[r0 + r] = sqrtf(v);   // exact global min
    if (lane == 15) tauP[r0 + r] = v;               // 16th-smallest lane-min
    float v2 = bitonic_sort64(mT[r], lane);
    if (lane == 15) tauT[r0 + r] = v2;
  }
}

// Guaranteed-exact fallback (fires only if >CAP candidates under tau; P~0).
__device__ float exact16_rowlist(const float4* __restrict__ base,
                                 float qx, float qy, float qz, int lane) {
  float a[KNN];
#pragma unroll
  for (int k = 0; k < KNN; ++k) a[k] = INFINITY;
  for (int s = 0; s < STEPS; ++s) {
    float d = sqd3(qx, qy, qz, base[s * 64 + lane]);
    if (d < a[KNN - 1]) {
      a[KNN - 1] = d;
#pragma unroll
      for (int k = KNN - 1; k > 0; --k) {
        float lo = fminf(a[k - 1], a[k]);
        float hi = fmaxf(a[k - 1], a[k]);
        a[k - 1] = lo; a[k] = hi;
      }
    }
  }
  float res = INFINITY;
#pragma unroll 1
  for (int r = 0; r < KNN; ++r) {
    float v = a[0];
    int idx = lane;
#pragma unroll
    for (int s = 1; s < 64; s <<= 1) {
      float ov = __shfl_xor(v, s, 64);
      int oi = __shfl_xor(idx, s, 64);
      bool take = (ov < v) || (ov == v && oi < idx);
      v = take ? ov : v;
      idx = take ? oi : idx;
    }
    if (lane == r) res = v;
    if (lane == idx) {
#pragma unroll
      for (int k = 0; k < KNN - 1; ++k) a[k] = a[k + 1];
      a[KNN - 1] = INFINITY;
    }
  }
  return res;
}

// Pass 2: collect candidates with d <= tau per row per list (4 rows/wave,
// wave-uniform __any skip, ballot/mbcnt compaction — no LDS atomics, counts
// live wave-uniform in registers), then one bitonic sort-64 -> exact
// ascending 16-NN of both lists -> density contribution.
// Trailing CMB_BLOCKS blocks combine the pass1 column-min partials -> mincol.
__global__ __launch_bounds__(128) void knn_kernel(
    const float4* __restrict__ P4, const float4* __restrict__ T4,
    const float* __restrict__ tauP, const float* __restrict__ tauT,
    const unsigned* __restrict__ colmin_part, float* __restrict__ mincol_arr,
    float* __restrict__ density_arr) {
  if (blockIdx.x >= K_BLOCKS) {
    // colmin combine: 128 blocks x 128 threads cover NROWS columns
    int idx = (blockIdx.x - K_BLOCKS) * 128 + threadIdx.x;
    int b = idx >> 13, j = idx & (NPTS - 1);
    const unsigned* base = colmin_part + (size_t)b * P1_PER_BATCH * NPTS + j;
    unsigned m = INF_BITS;
#pragma unroll 8
    for (int p = 0; p < P1_PER_BATCH; ++p) m = min(m, base[(size_t)p * NPTS]);
    mincol_arr[idx] = sqrtf(__uint_as_float(m));
    return;
  }
  __shared__ float col[K_ROWS][2][CAP];   // 4 KB
  const int wave = threadIdx.x >> 6, lane = threadIdx.x & 63;
  const int row0 = blockIdx.x * K_ROWS;
  const int b = row0 >> 13;
  const int i0 = row0 & (NPTS - 1);
  const float4* Pb = P4 + ((size_t)b << 13);
  const float4* Tb = T4 + ((size_t)b << 13);
  const int wr = wave * K_G;

  float qx[K_G], qy[K_G], qz[K_G], tP[K_G], tT[K_G];
  int cntP[K_G], cntT[K_G];               // wave-uniform
#pragma unroll
  for (int r = 0; r < K_G; ++r) {
    float4 q = Tb[i0 + wr + r];
    qx[r] = q.x; qy[r] = q.y; qz[r] = q.z;
    tP[r] = tauP[row0 + wr + r];
    tT[r] = tauT[row0 + wr + r];
    cntP[r] = 0; cntT[r] = 0;
  }

  const float4* pP = Pb + lane;
  const float4* pT = Tb + lane;
  float4 cP = pP[0], cT = pT[0];
  for (int s = 0; s < STEPS; ++s) {
    float4 nP = pP[64], nT = pT[64];      // imm offset 1024 B
    float dP[K_G];
    bool hP = false;
#pragma unroll
    for (int r = 0; r < K_G; ++r) {
      dP[r] = sqd3(qx[r], qy[r], qz[r], cP);
      hP = hP || (dP[r] <= tP[r]);
    }
    if (__any(hP)) {                       // wave-uniform skip: ~50% of steps
#pragma unroll
      for (int r = 0; r < K_G; ++r) {
        unsigned long long mk = __ballot(dP[r] <= tP[r]);
        int ix = cntP[r] + lanerank(mk);
        if ((dP[r] <= tP[r]) && ix < CAP) col[wr + r][0][ix] = dP[r];
        cntP[r] += __popcll(mk);
      }
    }
    float dT[K_G];
    bool hT = false;
#pragma unroll
    for (int r = 0; r < K_G; ++r) {
      dT[r] = sqd3(qx[r], qy[r], qz[r], cT);
      hT = hT || (dT[r] <= tT[r]);
    }
    if (__any(hT)) {
#pragma unroll
      for (int r = 0; r < K_G; ++r) {
        unsigned long long mk = __ballot(dT[r] <= tT[r]);
        int ix = cntT[r] + lanerank(mk);
        if ((dT[r] <= tT[r]) && ix < CAP) col[wr + r][1][ix] = dT[r];
        cntT[r] += __popcll(mk);
      }
    }
    pP += 64; pT += 64;
    cP = nP; cT = nT;
  }

#pragma unroll 1
  for (int r = 0; r < K_G; ++r) {
    float vP = (lane < cntP[r]) ? col[wr + r][0][lane] : INFINITY;
    float vT = (lane < cntT[r]) ? col[wr + r][1][lane] : INFINITY;
    float sP = bitonic_sort64(vP, lane);
    float sT = bitonic_sort64(vT, lane);
    if (cntP[r] > CAP) sP = exact16_rowlist(Pb, qx[r], qy[r], qz[r], lane);
    if (cntT[r] > CAP) sT = exact16_rowlist(Tb, qx[r], qy[r], qz[r], lane);
    float term = (lane < KNN) ? fabsf(sqrtf(sP) - sqrtf(sT)) : 0.0f;
#pragma unroll
    for (int s = 1; s < 64; s <<= 1) term += __shfl_xor(term, s, 64);
    if (lane == 0) density_arr[row0 + wr + r] = term;
  }
}

// Deterministic single-block reduction -> 3 outputs.
__global__ __launch_bounds__(256) void finalize_kernel(
    const float* __restrict__ minrow_arr, const float* __restrict__ mincol_arr,
    const float* __restrict__ density_arr, float* __restrict__ out) {
  __shared__ double s1[256], s2[256], s3[256];
  const int t = threadIdx.x;
  double a = 0.0, b = 0.0, c = 0.0;
  for (int idx = t; idx < NROWS; idx += 256) {
    a += (double)minrow_arr[idx];
    b += (double)mincol_arr[idx];
    c += (double)density_arr[idx];
  }
  s1[t] = a; s2[t] = b; s3[t] = c;
  __syncthreads();
  for (int off = 128; off > 0; off >>= 1) {
    if (t < off) { s1[t] += s1[t + off]; s2[t] += s2[t + off]; s3[t] += s3[t + off]; }
    __syncthreads();
  }
  if (t == 0) {
    double shape = 0.5 * (s1[0] + s2[0]) / (double)NROWS;
    double dens = s3[0] / ((double)NROWS * KNN);
    out[0] = (float)(shape + dens);  // data_loss
    out[1] = (float)shape;           // shape_loss
    out[2] = (float)dens;            // density_loss
  }
}

extern "C" void kernel_launch(void* const* d_in, const int* in_sizes, int n_in,
                              void* d_out, int out_size, void* d_ws, size_t ws_size,
                              hipStream_t stream) {
  (void)in_sizes; (void)n_in; (void)out_size; (void)ws_size;
  const float* yp = (const float*)d_in[0];  // y_pred [B, N, 3]
  const float* yt = (const float*)d_in[1];  // y_true [B, N, 3]
  float* ws = (float*)d_ws;
  // NOTE: array order matters — pass1/knn prefetch up to 2 steps (128 float4)
  // past a batch slice; P4 is followed by T4, T4 by tauP/tauT: always mapped.
  float4* P4 = (float4*)ws;                           // NROWS float4
  float4* T4 = (float4*)(ws + 4 * NROWS);             // NROWS float4
  float* tauP = ws + 8 * NROWS;                       // NROWS
  float* tauT = tauP + NROWS;
  float* minrow_arr = tauT + NROWS;
  float* mincol_arr = minrow_arr + NROWS;
  float* density_arr = mincol_arr + NROWS;
  unsigned* colmin_part = (unsigned*)(density_arr + NROWS);  // P1_BLOCKS*NPTS u32 (8 MB)
  float* out = (float*)d_out;

  repack_kernel<<<NROWS / 256, 256, 0, stream>>>(yp, yt, P4, T4);
  pass1_kernel<<<P1_BLOCKS, 1024, 0, stream>>>(P4, T4, tauP, tauT, minrow_arr, colmin_part);
  knn_kernel<<<K_BLOCKS + CMB_BLOCKS, 128, 0, stream>>>(P4, T4, tauP, tauT,
                                                        colmin_part, mincol_arr, density_arr);
  finalize_kernel<<<1, 256, 0, stream>>>(minrow_arr, mincol_arr, density_arr, out);
}